// Round 2
// baseline (1134.182 us; speedup 1.0000x reference)
//
#include <hip/hip_runtime.h>
#include <cstring>
#include <cmath>
#include <cstdint>

#define N_TOK 65536
#define DIN 128
#define HD 64
#define TN 12
#define ON 3
#define NHOPS 4
#define TPB 256
#define NCAT 13

struct HopConst {
  float w[TN][ON];     // softmax mixture weights per temper
  unsigned ck0, ck1;   // categorical key for this hop
  int last_hop;
};

// ---- threefry2x32 (exact JAX semantics) ----
__host__ __device__ __forceinline__ void tf2x32(unsigned k0, unsigned k1,
                                                unsigned x0, unsigned x1,
                                                unsigned& o0, unsigned& o1) {
  unsigned ks2 = k0 ^ k1 ^ 0x1BD11BDAu;
  x0 += k0; x1 += k1;
#define TFR(r) { x0 += x1; x1 = (x1 << (r)) | (x1 >> (32 - (r))); x1 ^= x0; }
  TFR(13) TFR(15) TFR(26) TFR(6)
  x0 += k1;  x1 += ks2 + 1u;
  TFR(17) TFR(29) TFR(16) TFR(24)
  x0 += ks2; x1 += k0 + 2u;
  TFR(13) TFR(15) TFR(26) TFR(6)
  x0 += k0;  x1 += k1 + 3u;
  TFR(17) TFR(29) TFR(16) TFR(24)
  x0 += k1;  x1 += ks2 + 4u;
  TFR(13) TFR(15) TFR(26) TFR(6)
  x0 += ks2; x1 += k0 + 5u;
#undef TFR
  o0 = x0; o1 = x1;
}

// partitionable-mode 32-bit random bits for element with linear index j (< 2^32):
// bits = o0 ^ o1 of threefry2x32(key, (hi=0, lo=j))
__host__ __device__ __forceinline__ unsigned tf_bits32(unsigned k0, unsigned k1, unsigned j) {
  unsigned o0, o1;
  tf2x32(k0, k1, 0u, j, o0, o1);
  return o0 ^ o1;
}

// ---- kernels ----

// proj: states = x @ proj_W + proj_b; init tempers/done; histogram cnt0
__global__ __launch_bounds__(TPB, 2) void k_init(
    const float* __restrict__ x, const float* __restrict__ pW,
    const float* __restrict__ pb, const int* __restrict__ itemp,
    float* __restrict__ states, int* __restrict__ tempers,
    int* __restrict__ done, int* __restrict__ cnt0)
{
  __shared__ int lcnt[TN];
  const int tid = threadIdx.x;
  if (tid < TN) lcnt[tid] = 0;
  __syncthreads();
  const int n = blockIdx.x * TPB + tid;
  float acc[HD];
  #pragma unroll
  for (int k = 0; k < HD; ++k) acc[k] = pb[k];
  const float* xrow = x + (size_t)n * DIN;
  for (int d4 = 0; d4 < DIN / 4; ++d4) {
    const float4 xv = *(const float4*)(xrow + d4 * 4);
    const float xs[4] = {xv.x, xv.y, xv.z, xv.w};
    #pragma unroll
    for (int dd = 0; dd < 4; ++dd) {
      const float* wr = pW + (d4 * 4 + dd) * HD;   // wave-uniform -> s_load
      #pragma unroll
      for (int k = 0; k < HD; ++k) acc[k] = fmaf(xs[dd], wr[k], acc[k]);
    }
  }
  float* srow = states + (size_t)n * HD;
  #pragma unroll
  for (int k4 = 0; k4 < HD / 4; ++k4) {
    float4 v; v.x = acc[k4*4]; v.y = acc[k4*4+1]; v.z = acc[k4*4+2]; v.w = acc[k4*4+3];
    *(float4*)(srow + k4 * 4) = v;
  }
  const int t = itemp[n];
  tempers[n] = t;
  done[n] = 0;
  atomicAdd(&lcnt[t], 1);
  __syncthreads();
  if (tid < TN && lcnt[tid] > 0) atomicAdd(&cnt0[tid], lcnt[tid]);
}

// 256-padded prefix offsets over temper counts
__global__ void k_prefix(const int* __restrict__ cnt, int* __restrict__ offp) {
  if (threadIdx.x == 0 && blockIdx.x == 0) {
    int o = 0;
    for (int t = 0; t < TN; ++t) { offp[t] = o; o += (cnt[t] + TPB - 1) & ~(TPB - 1); }
    offp[TN] = o;
  }
}

// scatter active tokens into per-temper compact regions
__global__ __launch_bounds__(TPB) void k_scatter(
    const int* __restrict__ tempers, const int* __restrict__ done,
    const int* __restrict__ offp, int* __restrict__ cursor, int* __restrict__ compact)
{
  __shared__ int lcnt[TN], lbase[TN];
  const int tid = threadIdx.x;
  if (tid < TN) lcnt[tid] = 0;
  __syncthreads();
  const int n = blockIdx.x * TPB + tid;
  int t = -1, lpos = 0;
  if (!done[n]) { t = tempers[n]; lpos = atomicAdd(&lcnt[t], 1); }
  __syncthreads();
  if (tid < TN && lcnt[tid] > 0) lbase[tid] = atomicAdd(&cursor[tid], lcnt[tid]);
  __syncthreads();
  if (t >= 0) compact[offp[t] + lbase[t] + lpos] = n;
}

// main per-hop kernel: temper MLP + routing + categorical sample + update
__global__ __launch_bounds__(TPB, 2) void k_hop(
    float* __restrict__ states, int* __restrict__ tempers, int* __restrict__ done,
    const int* __restrict__ compact, const int* __restrict__ cnt,
    const int* __restrict__ offp,
    const float* __restrict__ W1, const float* __restrict__ b1,
    const float* __restrict__ W2, const float* __restrict__ b2,
    const float* __restrict__ rW1, const float* __restrict__ rb1,
    const float* __restrict__ rW2, const float* __restrict__ rb2,
    int* __restrict__ cnt_next, HopConst hc)
{
  // 64KB: per-thread column-private scratch (transposed -> conflict-free, no barriers)
  __shared__ float xch[HD][TPB];
  const int tid = threadIdx.x;
  const int bstart = blockIdx.x * TPB;
  if (bstart >= offp[TN]) return;
  int tt = 0;
  #pragma unroll
  for (int i = 1; i < TN; ++i) if (bstart >= offp[i]) tt = i;
  const int t = __builtin_amdgcn_readfirstlane(tt);
  const int cntt = cnt[t];
  const int pos = bstart + tid;
  const bool act = (pos - offp[t]) < cntt;
  const int token = compact[act ? pos : offp[t]];   // never read unwritten (poisoned) slots
  const float* __restrict__ srow = states + (size_t)token * HD;

  float out[HD];
  #pragma unroll
  for (int k = 0; k < HD; ++k) out[k] = 0.0f;

  #pragma unroll 1
  for (int o = 0; o < ON; ++o) {
    const float* W1o = W1 + ((size_t)(t * ON + o)) * HD * HD;
    const float* b1o = b1 + (t * ON + o) * HD;
    // layer 1 -> h1 (LDS), two k-halves keep acc static & SGPR pressure sane
    #pragma unroll
    for (int kh = 0; kh < 2; ++kh) {
      float acc[32];
      #pragma unroll
      for (int j = 0; j < 32; ++j) acc[j] = b1o[kh * 32 + j];
      for (int h4 = 0; h4 < HD / 4; ++h4) {
        const float4 sv = *(const float4*)(srow + h4 * 4);
        const float ss[4] = {sv.x, sv.y, sv.z, sv.w};
        #pragma unroll
        for (int hh = 0; hh < 4; ++hh) {
          const float* wr = W1o + (h4 * 4 + hh) * HD + kh * 32;   // uniform -> s_load
          #pragma unroll
          for (int j = 0; j < 32; ++j) acc[j] = fmaf(ss[hh], wr[j], acc[j]);
        }
      }
      #pragma unroll
      for (int j = 0; j < 32; ++j) xch[kh * 32 + j][tid] = fmaxf(acc[j], 0.0f);
    }
    // layer 2 -> out += w_o * relu(h1 @ W2 + b2)
    const float* W2o = W2 + ((size_t)(t * ON + o)) * HD * HD;
    const float* b2o = b2 + (t * ON + o) * HD;
    const float wo = hc.w[t][o];
    #pragma unroll
    for (int kh = 0; kh < 2; ++kh) {
      float acc[32];
      #pragma unroll
      for (int j = 0; j < 32; ++j) acc[j] = b2o[kh * 32 + j];
      for (int h = 0; h < HD; ++h) {
        const float hv = xch[h][tid];
        const float* wr = W2o + h * HD + kh * 32;
        #pragma unroll
        for (int j = 0; j < 32; ++j) acc[j] = fmaf(hv, wr[j], acc[j]);
      }
      #pragma unroll
      for (int j = 0; j < 32; ++j)
        out[kh * 32 + j] = fmaf(wo, fmaxf(acc[j], 0.0f), out[kh * 32 + j]);
    }
  }

  if (act) {
    float* wrow = states + (size_t)token * HD;
    #pragma unroll
    for (int k4 = 0; k4 < HD / 4; ++k4) {
      float4 v; v.x = out[k4*4]; v.y = out[k4*4+1]; v.z = out[k4*4+2]; v.w = out[k4*4+3];
      *(float4*)(wrow + k4 * 4) = v;
    }
  }

  if (hc.last_hop) return;   // routing result unused on final hop

  // routing: r1 = relu(out @ rW1 + rb1); logits = r1 @ rW2 + rb2
  #pragma unroll
  for (int k = 0; k < HD; ++k) xch[k][tid] = out[k];
  float r1[HD];
  #pragma unroll
  for (int kh = 0; kh < 2; ++kh) {
    float acc[32];
    #pragma unroll
    for (int j = 0; j < 32; ++j) acc[j] = rb1[kh * 32 + j];
    for (int h = 0; h < HD; ++h) {
      const float ov = xch[h][tid];
      const float* wr = rW1 + h * HD + kh * 32;
      #pragma unroll
      for (int j = 0; j < 32; ++j) acc[j] = fmaf(ov, wr[j], acc[j]);
    }
    #pragma unroll
    for (int j = 0; j < 32; ++j) r1[kh * 32 + j] = fmaxf(acc[j], 0.0f);
  }
  #pragma unroll
  for (int k = 0; k < HD; ++k) xch[k][tid] = r1[k];

  float lg[NCAT];
  #pragma unroll
  for (int c = 0; c < NCAT; ++c) lg[c] = rb2[c];
  for (int k = 0; k < HD; ++k) {
    const float rv = xch[k][tid];
    const float* wr = rW2 + k * NCAT;
    #pragma unroll
    for (int c = 0; c < NCAT; ++c) lg[c] = fmaf(rv, wr[c], lg[c]);
  }

  // gumbel-argmax categorical, JAX threefry_partitionable bit layout:
  // element j of shape (N,13): bits = o0 ^ o1 of tf(key, hi=0, lo=j)
  const unsigned jb = (unsigned)token * (unsigned)NCAT;
  float best = -3.0e38f; int bc = 0;
  #pragma unroll
  for (int c = 0; c < NCAT; ++c) {
    const unsigned bits = tf_bits32(hc.ck0, hc.ck1, jb + (unsigned)c);
    const float u = __uint_as_float((bits >> 9) | 0x3f800000u) - 1.0f;
    float val = u + 1.17549435e-38f;
    val = fmaxf(val, 1.17549435e-38f);
    const float g = -logf(-logf(val));
    const float sc = lg[c] + g;
    if (sc > best) { best = sc; bc = c; }   // strict > keeps first max (jnp.argmax)
  }

  // epilogue: reuse xch head as next-hop histogram (all xch reads are done)
  int* lcnt = (int*)&xch[0][0];
  __syncthreads();
  if (tid < TN) lcnt[tid] = 0;
  __syncthreads();
  if (act) {
    const int nt = bc < (TN - 1) ? bc : (TN - 1);
    tempers[token] = nt;
    if (bc == TN) done[token] = 1;
    else atomicAdd(&lcnt[nt], 1);
  }
  __syncthreads();
  if (tid < TN && lcnt[tid] > 0) atomicAdd(&cnt_next[tid], lcnt[tid]);
}

// pred = states @ pred_W + pred_b; err = mean((pred-x)^2). Wave per token.
__global__ __launch_bounds__(TPB, 2) void k_pred(
    const float* __restrict__ states, const float* __restrict__ x,
    const float* __restrict__ pW, const float* __restrict__ pb,
    float* __restrict__ pred, float* __restrict__ err)
{
  const int tid = threadIdx.x;
  const int lane = tid & 63;
  int n = blockIdx.x * 4 + (tid >> 6);
  n = __builtin_amdgcn_readfirstlane(n);
  const float* srow = states + (size_t)n * HD;
  float a0 = pb[lane], a1 = pb[64 + lane];
  for (int h = 0; h < HD; ++h) {
    const float sh = srow[h];                       // wave-uniform -> s_load
    a0 = fmaf(sh, pW[h * DIN + lane], a0);
    a1 = fmaf(sh, pW[h * DIN + 64 + lane], a1);
  }
  pred[(size_t)n * DIN + lane] = a0;
  pred[(size_t)n * DIN + 64 + lane] = a1;
  const float x0v = x[(size_t)n * DIN + lane];
  const float x1v = x[(size_t)n * DIN + 64 + lane];
  const float d0 = a0 - x0v, d1 = a1 - x1v;
  float s = fmaf(d0, d0, d1 * d1);
  #pragma unroll
  for (int off = 32; off > 0; off >>= 1) s += __shfl_xor(s, off, 64);
  if (lane == 0) err[n] = s * (1.0f / 128.0f);
}

// ---- host-side RNG constant derivation (deterministic, capture-safe) ----
static float host_erfinv(float xf) {     // XLA ErfInv32 (Giles) polynomial
  double x = xf;
  double w = -log1p(-x * x);
  double p;
  if (w < 5.0) {
    w -= 2.5;
    p = 2.81022636e-08;          p = 3.43273939e-07 + p * w;
    p = -3.5233877e-06 + p * w;  p = -4.39150654e-06 + p * w;
    p = 0.00021858087 + p * w;   p = -0.00125372503 + p * w;
    p = -0.00417768164 + p * w;  p = 0.246640727 + p * w;
    p = 1.50140941 + p * w;
  } else {
    w = sqrt(w) - 3.0;
    p = -0.000200214257;         p = 0.000100950558 + p * w;
    p = 0.00134934322 + p * w;   p = -0.00367342844 + p * w;
    p = 0.00573950773 + p * w;   p = -0.0076224613 + p * w;
    p = 0.00943887047 + p * w;   p = 1.00167406 + p * w;
    p = 2.83297682 + p * w;
  }
  return (float)(p * x);
}

static void build_hops(HopConst* hcs) {
  const float lo = nextafterf(-1.0f, 0.0f);       // -0.99999994
  const unsigned rk0 = 0u, rk1 = 42u;             // jax.random.key(42) -> [0,42]
  for (int hop = 0; hop < NHOPS; ++hop) {
    unsigned hk0, hk1;
    tf2x32(rk0, rk1, 0u, (unsigned)hop, hk0, hk1);          // fold_in(rkey, hop)
    for (int t = 0; t < TN; ++t) {
      unsigned tk0, tk1;
      tf2x32(hk0, hk1, 0u, (unsigned)t, tk0, tk1);          // fold_in(hkey, t)
      // partitionable random_bits, shape (3,): bits[i] = o0^o1 of tf(key, 0, i)
      double nrm[3];
      for (int i = 0; i < 3; ++i) {
        const unsigned bits = tf_bits32(tk0, tk1, (unsigned)i);
        unsigned ub = (bits >> 9) | 0x3f800000u;
        float f; memcpy(&f, &ub, 4);
        const float u01 = f - 1.0f;
        float val = u01 * 2.0f + lo;                        // (max-min)=2.0f exactly (RNE)
        if (val < lo) val = lo;
        const float ef = host_erfinv(val);
        nrm[i] = (double)(1.41421356f * ef);                // sqrt(2) fp32 const
      }
      const double m = fmax(nrm[0], fmax(nrm[1], nrm[2]));
      const double e0 = exp(nrm[0] - m), e1 = exp(nrm[1] - m), e2 = exp(nrm[2] - m);
      const double s = e0 + e1 + e2;
      hcs[hop].w[t][0] = (float)(e0 / s);
      hcs[hop].w[t][1] = (float)(e1 / s);
      hcs[hop].w[t][2] = (float)(e2 / s);
    }
    unsigned ck0, ck1;
    tf2x32(hk0, hk1, 0u, 10000u, ck0, ck1);                 // fold_in(hkey, 10000)
    hcs[hop].ck0 = ck0; hcs[hop].ck1 = ck1;
    hcs[hop].last_hop = (hop == NHOPS - 1) ? 1 : 0;
  }
}

extern "C" void kernel_launch(void* const* d_in, const int* in_sizes, int n_in,
                              void* d_out, int out_size, void* d_ws, size_t ws_size,
                              hipStream_t stream) {
  (void)in_sizes; (void)n_in; (void)out_size; (void)ws_size;
  const float* x    = (const float*)d_in[0];
  const float* pW   = (const float*)d_in[1];
  const float* pb   = (const float*)d_in[2];
  const float* W1   = (const float*)d_in[3];
  const float* b1   = (const float*)d_in[4];
  const float* W2   = (const float*)d_in[5];
  const float* b2   = (const float*)d_in[6];
  const float* rW1  = (const float*)d_in[7];
  const float* rb1  = (const float*)d_in[8];
  const float* rW2  = (const float*)d_in[9];
  const float* rb2  = (const float*)d_in[10];
  const float* pdW  = (const float*)d_in[11];
  const float* pdb  = (const float*)d_in[12];
  const int*   itmp = (const int*)d_in[13];

  // ws layout: [meta 1KB][tempers N][done N][compact N+TN*TPB][states N*64 f32]
  int* meta    = (int*)d_ws;                       // cnt[5][12] @0, cursor[4][12] @60, offp[4][13] @108
  int* tempers = (int*)((char*)d_ws + 1024);
  int* done    = tempers + N_TOK;
  int* compact = done + N_TOK;
  float* states = (float*)(compact + N_TOK + TN * TPB);

  HopConst hcs[NHOPS];
  build_hops(hcs);

  hipMemsetAsync(meta, 0, 160 * sizeof(int), stream);
  k_init<<<N_TOK / TPB, TPB, 0, stream>>>(x, pW, pb, itmp, states, tempers, done, meta);
  for (int h = 0; h < NHOPS; ++h) {
    int* cnt_h = meta + h * TN;
    int* cnt_n = meta + (h + 1) * TN;
    int* cur_h = meta + 60 + h * TN;
    int* off_h = meta + 108 + h * (TN + 1);
    k_prefix<<<1, 64, 0, stream>>>(cnt_h, off_h);
    k_scatter<<<N_TOK / TPB, TPB, 0, stream>>>(tempers, done, off_h, cur_h, compact);
    k_hop<<<N_TOK / TPB + TN, TPB, 0, stream>>>(states, tempers, done, compact, cnt_h, off_h,
        W1, b1, W2, b2, rW1, rb1, rW2, rb2, cnt_n, hcs[h]);
  }
  float* pred = (float*)d_out;
  float* errp = pred + (size_t)N_TOK * DIN;
  k_pred<<<N_TOK / 4, TPB, 0, stream>>>(states, x, pdW, pdb, pred, errp);
}

// Round 3
// 535.232 us; speedup vs baseline: 2.1190x; 2.1190x over previous
//
#include <hip/hip_runtime.h>
#include <cstring>
#include <cmath>
#include <cstdint>

#define N_TOK 65536
#define DIN 128
#define HD 64
#define TN 12
#define ON 3
#define NHOPS 4
#define TPB 256
#define TOKB 64          // tokens per k_hop block (4 threads/token)
#define NCAT 13

struct HopConst {
  float w[TN][ON];     // softmax mixture weights per temper
  unsigned ck0, ck1;   // categorical key for this hop
  int last_hop;
};

// ---- threefry2x32 (exact JAX semantics) ----
__host__ __device__ __forceinline__ void tf2x32(unsigned k0, unsigned k1,
                                                unsigned x0, unsigned x1,
                                                unsigned& o0, unsigned& o1) {
  unsigned ks2 = k0 ^ k1 ^ 0x1BD11BDAu;
  x0 += k0; x1 += k1;
#define TFR(r) { x0 += x1; x1 = (x1 << (r)) | (x1 >> (32 - (r))); x1 ^= x0; }
  TFR(13) TFR(15) TFR(26) TFR(6)
  x0 += k1;  x1 += ks2 + 1u;
  TFR(17) TFR(29) TFR(16) TFR(24)
  x0 += ks2; x1 += k0 + 2u;
  TFR(13) TFR(15) TFR(26) TFR(6)
  x0 += k0;  x1 += k1 + 3u;
  TFR(17) TFR(29) TFR(16) TFR(24)
  x0 += k1;  x1 += ks2 + 4u;
  TFR(13) TFR(15) TFR(26) TFR(6)
  x0 += ks2; x1 += k0 + 5u;
#undef TFR
  o0 = x0; o1 = x1;
}

// partitionable-mode 32-bit random bits, element j: o0^o1 of tf(key, 0, j)
__host__ __device__ __forceinline__ unsigned tf_bits32(unsigned k0, unsigned k1, unsigned j) {
  unsigned o0, o1;
  tf2x32(k0, k1, 0u, j, o0, o1);
  return o0 ^ o1;
}

// ---- kernels ----

// proj: states = x @ proj_W + proj_b; init tempers/done; histogram cnt0
__global__ __launch_bounds__(TPB, 2) void k_init(
    const float* __restrict__ x, const float* __restrict__ pW,
    const float* __restrict__ pb, const int* __restrict__ itemp,
    float* __restrict__ states, int* __restrict__ tempers,
    int* __restrict__ done, int* __restrict__ cnt0)
{
  __shared__ int lcnt[TN];
  const int tid = threadIdx.x;
  if (tid < TN) lcnt[tid] = 0;
  __syncthreads();
  const int n = blockIdx.x * TPB + tid;
  float acc[HD];
  #pragma unroll
  for (int k = 0; k < HD; ++k) acc[k] = pb[k];
  const float* xrow = x + (size_t)n * DIN;
  for (int d4 = 0; d4 < DIN / 4; ++d4) {
    const float4 xv = *(const float4*)(xrow + d4 * 4);
    const float xs[4] = {xv.x, xv.y, xv.z, xv.w};
    #pragma unroll
    for (int dd = 0; dd < 4; ++dd) {
      const float* wr = pW + (d4 * 4 + dd) * HD;   // wave-uniform -> s_load
      #pragma unroll
      for (int k = 0; k < HD; ++k) acc[k] = fmaf(xs[dd], wr[k], acc[k]);
    }
  }
  float* srow = states + (size_t)n * HD;
  #pragma unroll
  for (int k4 = 0; k4 < HD / 4; ++k4) {
    float4 v; v.x = acc[k4*4]; v.y = acc[k4*4+1]; v.z = acc[k4*4+2]; v.w = acc[k4*4+3];
    *(float4*)(srow + k4 * 4) = v;
  }
  const int t = itemp[n];
  tempers[n] = t;
  done[n] = 0;
  atomicAdd(&lcnt[t], 1);
  __syncthreads();
  if (tid < TN && lcnt[tid] > 0) atomicAdd(&cnt0[tid], lcnt[tid]);
}

// one-time weight transposes into ws (feature-major stripes for scalar streaming)
__global__ __launch_bounds__(TPB) void k_tr(
    const float* __restrict__ W1, const float* __restrict__ W2,
    const float* __restrict__ rW1, const float* __restrict__ rW2,
    float* __restrict__ W1T, float* __restrict__ W2T,
    float* __restrict__ rW1T, float* __restrict__ rW2T)
{
  const int i = blockIdx.x * TPB + threadIdx.x;
  if (i < TN * ON * HD * HD) {
    const int m = i >> 12, h = (i >> 6) & 63, j = i & 63;   // in: [m][h][j]
    W1T[(m << 12) + (j << 6) + h] = W1[i];                  // out: [m][j][h]
    W2T[(m << 12) + (j << 6) + h] = W2[i];
  }
  if (i < HD * HD) {
    const int h = i >> 6, j = i & 63;
    rW1T[(j << 6) + h] = rW1[i];
  }
  if (i < NCAT * HD) {
    const int c = i >> 6, h = i & 63;
    rW2T[i] = rW2[h * NCAT + c];                            // rW2T[c][h]
  }
}

// 64-padded prefix offsets over temper counts
__global__ void k_prefix(const int* __restrict__ cnt, int* __restrict__ offp) {
  if (threadIdx.x == 0 && blockIdx.x == 0) {
    int o = 0;
    for (int t = 0; t < TN; ++t) { offp[t] = o; o += (cnt[t] + TOKB - 1) & ~(TOKB - 1); }
    offp[TN] = o;
  }
}

// scatter active tokens into per-temper compact regions
__global__ __launch_bounds__(TPB) void k_scatter(
    const int* __restrict__ tempers, const int* __restrict__ done,
    const int* __restrict__ offp, int* __restrict__ cursor, int* __restrict__ compact)
{
  __shared__ int lcnt[TN], lbase[TN];
  const int tid = threadIdx.x;
  if (tid < TN) lcnt[tid] = 0;
  __syncthreads();
  const int n = blockIdx.x * TPB + tid;
  int t = -1, lpos = 0;
  if (!done[n]) { t = tempers[n]; lpos = atomicAdd(&lcnt[t], 1); }
  __syncthreads();
  if (tid < TN && lcnt[tid] > 0) lbase[tid] = atomicAdd(&cursor[tid], lcnt[tid]);
  __syncthreads();
  if (t >= 0) compact[offp[t] + lbase[t] + lpos] = n;
}

// main per-hop kernel: 4 threads per token (16 features each), transposed
// scalar weight stripes, LDS only for h1/out/r1 exchange (16 KB).
__global__ __launch_bounds__(TPB, 4) void k_hop(
    float* __restrict__ states, int* __restrict__ tempers, int* __restrict__ done,
    const int* __restrict__ compact, const int* __restrict__ cnt,
    const int* __restrict__ offp,
    const float* __restrict__ W1T, const float* __restrict__ b1,
    const float* __restrict__ W2T, const float* __restrict__ b2,
    const float* __restrict__ rW1T, const float* __restrict__ rb1,
    const float* __restrict__ rW2T, const float* __restrict__ rb2,
    int* __restrict__ cnt_next, HopConst hc)
{
  __shared__ float xch[HD][TOKB];     // [feature][token-slot], conflict-free columns
  __shared__ int lcnt[TN];
  const int tid = threadIdx.x;
  const int tokloc = tid & 63;
  const int fg = __builtin_amdgcn_readfirstlane(tid >> 6);  // wave-uniform feature group
  const int fbase = fg * 16;
  const int bstart = blockIdx.x * TOKB;
  if (bstart >= offp[TN]) return;
  int tt = 0;
  #pragma unroll
  for (int i = 1; i < TN; ++i) if (bstart >= offp[i]) tt = i;
  const int t = __builtin_amdgcn_readfirstlane(tt);
  const int cntt = cnt[t];
  const bool act = (bstart + tokloc - offp[t]) < cntt;
  const int token = compact[act ? (bstart + tokloc) : offp[t]];
  const float* __restrict__ srow = states + (size_t)token * HD;

  float out[16];
  #pragma unroll
  for (int j = 0; j < 16; ++j) out[j] = 0.0f;

  #pragma unroll 1
  for (int o = 0; o < ON; ++o) {
    const size_t mb = ((size_t)(t * ON + o)) << 12;
    const float* __restrict__ W1o = W1T + mb;             // [j][h] stripes
    const float* __restrict__ b1o = b1 + (t * ON + o) * HD;
    float acc[16];
    #pragma unroll
    for (int j = 0; j < 16; ++j) acc[j] = b1o[fbase + j];
    for (int h4 = 0; h4 < HD / 4; ++h4) {
      const float4 sv = *(const float4*)(srow + h4 * 4);
      const float ss[4] = {sv.x, sv.y, sv.z, sv.w};
      #pragma unroll
      for (int hh = 0; hh < 4; ++hh)
        #pragma unroll
        for (int j = 0; j < 16; ++j)
          acc[j] = fmaf(ss[hh], W1o[(fbase + j) * HD + h4 * 4 + hh], acc[j]);
    }
    #pragma unroll
    for (int j = 0; j < 16; ++j) xch[fbase + j][tokloc] = fmaxf(acc[j], 0.0f);
    __syncthreads();                                      // h1 ready for all fg

    const float* __restrict__ W2o = W2T + mb;
    const float* __restrict__ b2o = b2 + (t * ON + o) * HD;
    float acc2[16];
    #pragma unroll
    for (int j = 0; j < 16; ++j) acc2[j] = b2o[fbase + j];
    for (int h4 = 0; h4 < HD / 4; ++h4) {
      float hv[4];
      #pragma unroll
      for (int hh = 0; hh < 4; ++hh) hv[hh] = xch[h4 * 4 + hh][tokloc];
      #pragma unroll
      for (int hh = 0; hh < 4; ++hh)
        #pragma unroll
        for (int j = 0; j < 16; ++j)
          acc2[j] = fmaf(hv[hh], W2o[(fbase + j) * HD + h4 * 4 + hh], acc2[j]);
    }
    const float wo = hc.w[t][o];
    #pragma unroll
    for (int j = 0; j < 16; ++j) out[j] = fmaf(wo, fmaxf(acc2[j], 0.0f), out[j]);
    __syncthreads();                                      // xch reads done before next-o write
  }

  if (act) {
    float* wrow = states + (size_t)token * HD + fbase;
    #pragma unroll
    for (int q = 0; q < 4; ++q) {
      float4 v; v.x = out[q*4]; v.y = out[q*4+1]; v.z = out[q*4+2]; v.w = out[q*4+3];
      *(float4*)(wrow + q * 4) = v;
    }
  }

  if (hc.last_hop) return;    // uniform exit; routing result unused

  // routing: exchange out through xch, r1 = relu(out @ rW1 + rb1)
  #pragma unroll
  for (int j = 0; j < 16; ++j) xch[fbase + j][tokloc] = out[j];
  __syncthreads();
  float acc3[16];
  #pragma unroll
  for (int j = 0; j < 16; ++j) acc3[j] = rb1[fbase + j];
  for (int h4 = 0; h4 < HD / 4; ++h4) {
    float hv[4];
    #pragma unroll
    for (int hh = 0; hh < 4; ++hh) hv[hh] = xch[h4 * 4 + hh][tokloc];
    #pragma unroll
    for (int hh = 0; hh < 4; ++hh)
      #pragma unroll
      for (int j = 0; j < 16; ++j)
        acc3[j] = fmaf(hv[hh], rW1T[(fbase + j) * HD + h4 * 4 + hh], acc3[j]);
  }
  __syncthreads();            // out reads done; overwrite xch with r1
  #pragma unroll
  for (int j = 0; j < 16; ++j) xch[fbase + j][tokloc] = fmaxf(acc3[j], 0.0f);
  __syncthreads();

  // wave 0: logits = r1 @ rW2 + rb2, gumbel-argmax sample
  int bc = 0;
  if (fg == 0) {
    float lg[NCAT];
    #pragma unroll
    for (int c = 0; c < NCAT; ++c) lg[c] = rb2[c];
    for (int h4 = 0; h4 < HD / 4; ++h4) {
      float hv[4];
      #pragma unroll
      for (int hh = 0; hh < 4; ++hh) hv[hh] = xch[h4 * 4 + hh][tokloc];
      #pragma unroll
      for (int hh = 0; hh < 4; ++hh)
        #pragma unroll
        for (int c = 0; c < NCAT; ++c)
          lg[c] = fmaf(hv[hh], rW2T[c * HD + h4 * 4 + hh], lg[c]);
    }
    const unsigned jb = (unsigned)token * (unsigned)NCAT;
    float best = -3.0e38f;
    #pragma unroll
    for (int c = 0; c < NCAT; ++c) {
      const unsigned bits = tf_bits32(hc.ck0, hc.ck1, jb + (unsigned)c);
      const float u = __uint_as_float((bits >> 9) | 0x3f800000u) - 1.0f;
      float val = u + 1.17549435e-38f;
      val = fmaxf(val, 1.17549435e-38f);
      const float g = -logf(-logf(val));
      const float sc = lg[c] + g;
      if (sc > best) { best = sc; bc = c; }   // strict > keeps first max
    }
  }
  if (tid < TN) lcnt[tid] = 0;
  __syncthreads();
  if (fg == 0 && act) {
    const int nt = bc < (TN - 1) ? bc : (TN - 1);
    tempers[token] = nt;
    if (bc == TN) done[token] = 1;
    else atomicAdd(&lcnt[nt], 1);
  }
  __syncthreads();
  if (tid < TN && lcnt[tid] > 0) atomicAdd(&cnt_next[tid], lcnt[tid]);
}

// pred = states @ pred_W + pred_b; err = mean((pred-x)^2). Wave per token.
__global__ __launch_bounds__(TPB, 2) void k_pred(
    const float* __restrict__ states, const float* __restrict__ x,
    const float* __restrict__ pW, const float* __restrict__ pb,
    float* __restrict__ pred, float* __restrict__ err)
{
  const int tid = threadIdx.x;
  const int lane = tid & 63;
  int n = blockIdx.x * 4 + (tid >> 6);
  n = __builtin_amdgcn_readfirstlane(n);
  const float* srow = states + (size_t)n * HD;
  float a0 = pb[lane], a1 = pb[64 + lane];
  for (int h = 0; h < HD; ++h) {
    const float sh = srow[h];                       // wave-uniform -> s_load
    a0 = fmaf(sh, pW[h * DIN + lane], a0);
    a1 = fmaf(sh, pW[h * DIN + 64 + lane], a1);
  }
  pred[(size_t)n * DIN + lane] = a0;
  pred[(size_t)n * DIN + 64 + lane] = a1;
  const float x0v = x[(size_t)n * DIN + lane];
  const float x1v = x[(size_t)n * DIN + 64 + lane];
  const float d0 = a0 - x0v, d1 = a1 - x1v;
  float s = fmaf(d0, d0, d1 * d1);
  #pragma unroll
  for (int off = 32; off > 0; off >>= 1) s += __shfl_xor(s, off, 64);
  if (lane == 0) err[n] = s * (1.0f / 128.0f);
}

// ---- host-side RNG constant derivation (deterministic, capture-safe) ----
static float host_erfinv(float xf) {     // XLA ErfInv32 (Giles) polynomial
  double x = xf;
  double w = -log1p(-x * x);
  double p;
  if (w < 5.0) {
    w -= 2.5;
    p = 2.81022636e-08;          p = 3.43273939e-07 + p * w;
    p = -3.5233877e-06 + p * w;  p = -4.39150654e-06 + p * w;
    p = 0.00021858087 + p * w;   p = -0.00125372503 + p * w;
    p = -0.00417768164 + p * w;  p = 0.246640727 + p * w;
    p = 1.50140941 + p * w;
  } else {
    w = sqrt(w) - 3.0;
    p = -0.000200214257;         p = 0.000100950558 + p * w;
    p = 0.00134934322 + p * w;   p = -0.00367342844 + p * w;
    p = 0.00573950773 + p * w;   p = -0.0076224613 + p * w;
    p = 0.00943887047 + p * w;   p = 1.00167406 + p * w;
    p = 2.83297682 + p * w;
  }
  return (float)(p * x);
}

static void build_hops(HopConst* hcs) {
  const float lo = nextafterf(-1.0f, 0.0f);       // -0.99999994
  const unsigned rk0 = 0u, rk1 = 42u;             // jax.random.key(42) -> [0,42]
  for (int hop = 0; hop < NHOPS; ++hop) {
    unsigned hk0, hk1;
    tf2x32(rk0, rk1, 0u, (unsigned)hop, hk0, hk1);          // fold_in(rkey, hop)
    for (int t = 0; t < TN; ++t) {
      unsigned tk0, tk1;
      tf2x32(hk0, hk1, 0u, (unsigned)t, tk0, tk1);          // fold_in(hkey, t)
      double nrm[3];
      for (int i = 0; i < 3; ++i) {
        const unsigned bits = tf_bits32(tk0, tk1, (unsigned)i);
        unsigned ub = (bits >> 9) | 0x3f800000u;
        float f; memcpy(&f, &ub, 4);
        const float u01 = f - 1.0f;
        float val = u01 * 2.0f + lo;                        // (max-min)=2.0f exactly (RNE)
        if (val < lo) val = lo;
        const float ef = host_erfinv(val);
        nrm[i] = (double)(1.41421356f * ef);                // sqrt(2) fp32 const
      }
      const double m = fmax(nrm[0], fmax(nrm[1], nrm[2]));
      const double e0 = exp(nrm[0] - m), e1 = exp(nrm[1] - m), e2 = exp(nrm[2] - m);
      const double s = e0 + e1 + e2;
      hcs[hop].w[t][0] = (float)(e0 / s);
      hcs[hop].w[t][1] = (float)(e1 / s);
      hcs[hop].w[t][2] = (float)(e2 / s);
    }
    unsigned ck0, ck1;
    tf2x32(hk0, hk1, 0u, 10000u, ck0, ck1);                 // fold_in(hkey, 10000)
    hcs[hop].ck0 = ck0; hcs[hop].ck1 = ck1;
    hcs[hop].last_hop = (hop == NHOPS - 1) ? 1 : 0;
  }
}

extern "C" void kernel_launch(void* const* d_in, const int* in_sizes, int n_in,
                              void* d_out, int out_size, void* d_ws, size_t ws_size,
                              hipStream_t stream) {
  (void)in_sizes; (void)n_in; (void)out_size; (void)ws_size;
  const float* x    = (const float*)d_in[0];
  const float* pW   = (const float*)d_in[1];
  const float* pb   = (const float*)d_in[2];
  const float* W1   = (const float*)d_in[3];
  const float* b1   = (const float*)d_in[4];
  const float* W2   = (const float*)d_in[5];
  const float* b2   = (const float*)d_in[6];
  const float* rW1  = (const float*)d_in[7];
  const float* rb1  = (const float*)d_in[8];
  const float* rW2  = (const float*)d_in[9];
  const float* rb2  = (const float*)d_in[10];
  const float* pdW  = (const float*)d_in[11];
  const float* pdb  = (const float*)d_in[12];
  const int*   itmp = (const int*)d_in[13];

  // ws layout: [meta 1KB][tempers N][done N][compact N+TN*64][states N*64]
  //            [W1T 147456][W2T 147456][rW1T 4096][rW2T 832]
  int* meta    = (int*)d_ws;
  int* tempers = (int*)((char*)d_ws + 1024);
  int* done    = tempers + N_TOK;
  int* compact = done + N_TOK;
  float* states = (float*)(compact + N_TOK + TN * TOKB);
  float* W1T  = states + (size_t)N_TOK * HD;
  float* W2T  = W1T + TN * ON * HD * HD;
  float* rW1T = W2T + TN * ON * HD * HD;
  float* rW2T = rW1T + HD * HD;

  HopConst hcs[NHOPS];
  build_hops(hcs);

  hipMemsetAsync(meta, 0, 160 * sizeof(int), stream);
  k_tr<<<(TN * ON * HD * HD + TPB - 1) / TPB, TPB, 0, stream>>>(
      W1, W2, rW1, rW2, W1T, W2T, rW1T, rW2T);
  k_init<<<N_TOK / TPB, TPB, 0, stream>>>(x, pW, pb, itmp, states, tempers, done, meta);
  for (int h = 0; h < NHOPS; ++h) {
    int* cnt_h = meta + h * TN;
    int* cnt_n = meta + (h + 1) * TN;
    int* cur_h = meta + 60 + h * TN;
    int* off_h = meta + 108 + h * (TN + 1);
    k_prefix<<<1, 64, 0, stream>>>(cnt_h, off_h);
    k_scatter<<<N_TOK / TPB, TPB, 0, stream>>>(tempers, done, off_h, cur_h, compact);
    k_hop<<<N_TOK / TOKB + TN, TPB, 0, stream>>>(states, tempers, done, compact, cnt_h, off_h,
        W1T, b1, W2T, b2, rW1T, rb1, rW2T, rb2, cnt_n, hcs[h]);
  }
  float* pred = (float*)d_out;
  float* errp = pred + (size_t)N_TOK * DIN;
  k_pred<<<N_TOK / 4, TPB, 0, stream>>>(states, x, pdW, pdb, pred, errp);
}